// Round 1
// baseline (2862.862 us; speedup 1.0000x reference)
//
#include <hip/hip_runtime.h>
#include <hip/hip_bf16.h>

// GCN 2-layer: h1 = relu(scatter(x@w1) + b1); out = scatter(h1@w2) + b2
// Scatter = edge-weighted gather from src, atomic-add into dst.
// N=100000, E=1600000, IN=128, HID=64, OUT=64, all fp32.

#define N_NODES 100000
#define N_EDGES 1600000

// ---------------------------------------------------------------------------
// GEMM: Y[n_rows,64] = f(X[n_rows,K]) @ W[K,64]
// f = identity (FUSE=false) or relu(x + bias[k]) (FUSE=true, bias over K dim)
// Tile: 32 rows x 64 cols per 256-thread block; thread = 2 rows x 4 cols.
// LDS: sW[K][64] (float4-read per k), sX[32][K+4] (pad 4 floats, bcast reads).
// ---------------------------------------------------------------------------
template<int K, bool FUSE>
__global__ __launch_bounds__(256) void gcn_gemm(
    const float* __restrict__ X, const float* __restrict__ W,
    const float* __restrict__ bias, float* __restrict__ Y)
{
    __shared__ float sW[K * 64];
    __shared__ float sX[32 * (K + 4)];
    const int tid  = threadIdx.x;
    const int row0 = blockIdx.x * 32;

    // stage W (K*64 floats, contiguous)
    #pragma unroll
    for (int i = tid * 4; i < K * 64; i += 256 * 4) {
        *(float4*)(sW + i) = *(const float4*)(W + i);
    }
    // stage X tile (32 x K), fused bias+relu for layer 2
    #pragma unroll
    for (int i = tid; i < 32 * (K / 4); i += 256) {
        int r  = i / (K / 4);
        int c4 = (i % (K / 4)) * 4;
        float4 v = *(const float4*)(X + (size_t)(row0 + r) * K + c4);
        if (FUSE) {
            v.x = fmaxf(v.x + bias[c4 + 0], 0.f);
            v.y = fmaxf(v.y + bias[c4 + 1], 0.f);
            v.z = fmaxf(v.z + bias[c4 + 2], 0.f);
            v.w = fmaxf(v.w + bias[c4 + 3], 0.f);
        }
        *(float4*)(sX + r * (K + 4) + c4) = v;
    }
    __syncthreads();

    const int c0 = (tid & 15) * 4;   // col 0..60
    const int r0 = (tid >> 4) * 2;   // row 0..30
    float acc00 = 0.f, acc01 = 0.f, acc02 = 0.f, acc03 = 0.f;
    float acc10 = 0.f, acc11 = 0.f, acc12 = 0.f, acc13 = 0.f;

    #pragma unroll 8
    for (int k = 0; k < K; ++k) {
        float4 wv = *(const float4*)(sW + k * 64 + c0);
        float x0 = sX[r0 * (K + 4) + k];
        float x1 = sX[(r0 + 1) * (K + 4) + k];
        acc00 = fmaf(x0, wv.x, acc00);
        acc01 = fmaf(x0, wv.y, acc01);
        acc02 = fmaf(x0, wv.z, acc02);
        acc03 = fmaf(x0, wv.w, acc03);
        acc10 = fmaf(x1, wv.x, acc10);
        acc11 = fmaf(x1, wv.y, acc11);
        acc12 = fmaf(x1, wv.z, acc12);
        acc13 = fmaf(x1, wv.w, acc13);
    }

    float4 o0 = make_float4(acc00, acc01, acc02, acc03);
    float4 o1 = make_float4(acc10, acc11, acc12, acc13);
    *(float4*)(Y + (size_t)(row0 + r0)     * 64 + c0) = o0;
    *(float4*)(Y + (size_t)(row0 + r0 + 1) * 64 + c0) = o1;
}

// ---------------------------------------------------------------------------
// Scatter: out[dst[e]][c] += H[src[e]][c] * ew[e]  for c in [0,64)
// 16 threads per edge, float4 per thread, 4 atomicAdds.
// ---------------------------------------------------------------------------
__global__ __launch_bounds__(256) void gcn_scatter(
    const float* __restrict__ H, const int* __restrict__ src,
    const int* __restrict__ dst, const float* __restrict__ ew,
    float* __restrict__ out, int n_edges)
{
    int t = blockIdx.x * 256 + threadIdx.x;
    int e = t >> 4;
    if (e >= n_edges) return;
    int c = (t & 15) * 4;
    int s = src[e];
    int d = dst[e];
    float w = ew[e];
    float4 v = *(const float4*)(H + (size_t)s * 64 + c);
    float* o = out + (size_t)d * 64 + c;
    atomicAdd(o + 0, v.x * w);
    atomicAdd(o + 1, v.y * w);
    atomicAdd(o + 2, v.z * w);
    atomicAdd(o + 3, v.w * w);
}

// out[n][c] = b2[c]  (vectorized; 64 cols = 16 float4s)
__global__ __launch_bounds__(256) void gcn_init_out(
    float* __restrict__ out, const float* __restrict__ b2, int n4)
{
    int i = blockIdx.x * 256 + threadIdx.x;
    if (i < n4) ((float4*)out)[i] = ((const float4*)b2)[i & 15];
}

extern "C" void kernel_launch(void* const* d_in, const int* in_sizes, int n_in,
                              void* d_out, int out_size, void* d_ws, size_t ws_size,
                              hipStream_t stream) {
    const float* x   = (const float*)d_in[0];
    const int*   ei  = (const int*)  d_in[1];
    const float* ew  = (const float*)d_in[2];
    const float* w1  = (const float*)d_in[3];
    const float* b1  = (const float*)d_in[4];
    const float* w2  = (const float*)d_in[5];
    const float* b2  = (const float*)d_in[6];
    float* out = (float*)d_out;

    const int N = N_NODES, E = N_EDGES;
    const int* src = ei;       // edge_index[0]
    const int* dst = ei + E;   // edge_index[1]

    const size_t feat_bytes = (size_t)N * 64 * sizeof(float);  // 25.6 MB
    float* bufA = (float*)d_ws;                          // h, then h2
    float* bufB = (float*)((char*)d_ws + feat_bytes);    // agg1

    // agg1 = 0 (ws is poisoned each call)
    hipMemsetAsync(bufB, 0, feat_bytes, stream);

    // h = x @ w1
    gcn_gemm<128, false><<<N / 32, 256, 0, stream>>>(x, w1, nullptr, bufA);
    // agg1 += scatter(h)
    gcn_scatter<<<(E * 16) / 256, 256, 0, stream>>>(bufA, src, dst, ew, bufB, E);
    // h2 = relu(agg1 + b1) @ w2   (reuses bufA)
    gcn_gemm<64, true><<<N / 32, 256, 0, stream>>>(bufB, w2, b1, bufA);
    // out = b2, then out += scatter(h2)
    gcn_init_out<<<(N * 16 + 255) / 256, 256, 0, stream>>>(out, b2, N * 16);
    gcn_scatter<<<(E * 16) / 256, 256, 0, stream>>>(bufA, src, dst, ew, out, E);
}

// Round 2
// 633.349 us; speedup vs baseline: 4.5202x; 4.5202x over previous
//
#include <hip/hip_runtime.h>
#include <hip/hip_bf16.h>

// GCN 2-layer: h1' = relu(S·(x@w1) + b1); out = S·(h1'@w2) + b2
// S = edge-weighted adjacency (gather src -> sum into dst).
// Strategy: build CSR-by-dst once per call (counting sort), then the two
// aggregations are gather-reduce (one wave per node, zero atomics, one
// plain store per node). Intermediates stored bf16 (halves gather traffic).
// N=100000, E=1600000, IN=128, HID=64, OUT=64.

#define N_NODES 100000
#define N_EDGES 1600000
#define SCAN_BLOCKS 391   // ceil(100000/256)

typedef unsigned short ushort_t;
typedef unsigned int uint_t;

static __device__ __forceinline__ float bf2f(ushort_t h) {
    return __uint_as_float(((uint_t)h) << 16);
}
static __device__ __forceinline__ ushort_t f2bf(float f) {
    uint_t u = __float_as_uint(f);
    u = (u + 0x7FFF + ((u >> 16) & 1)) >> 16;   // round-to-nearest-even
    return (ushort_t)u;
}

// ---------------------------------------------------------------------------
// CSR build: histogram -> scan -> placement
// ---------------------------------------------------------------------------
__global__ __launch_bounds__(256) void k_hist(
    const int* __restrict__ dst, int* __restrict__ hist, int E)
{
    int e = blockIdx.x * 256 + threadIdx.x;
    if (e < E) atomicAdd(&hist[dst[e]], 1);
}

// inclusive scan within 256-blocks; endoff[i] = partial inclusive, bsum[b] = block total
__global__ __launch_bounds__(256) void k_scan1(
    const int* __restrict__ hist, int* __restrict__ endoff,
    int* __restrict__ bsum, int N)
{
    __shared__ int s[256];
    int t = threadIdx.x;
    int i = blockIdx.x * 256 + t;
    int v = (i < N) ? hist[i] : 0;
    s[t] = v;
    #pragma unroll
    for (int off = 1; off < 256; off <<= 1) {
        __syncthreads();
        int add = (t >= off) ? s[t - off] : 0;
        __syncthreads();
        s[t] += add;
    }
    __syncthreads();
    if (i < N) endoff[i] = s[t];
    if (t == 255) bsum[blockIdx.x] = s[255];
}

// single block: bsum -> exclusive scan of block totals (in place)
__global__ __launch_bounds__(512) void k_scan2(int* __restrict__ bsum, int nb)
{
    __shared__ int s[512];
    int t = threadIdx.x;
    s[t] = (t < nb) ? bsum[t] : 0;
    #pragma unroll
    for (int off = 1; off < 512; off <<= 1) {
        __syncthreads();
        int add = (t >= off) ? s[t - off] : 0;
        __syncthreads();
        s[t] += add;
    }
    __syncthreads();
    if (t < nb) bsum[t] = (t == 0) ? 0 : s[t - 1];
}

// endoff[i] += bsum[block]; cur[i] = endoff[i]
__global__ __launch_bounds__(256) void k_scan3(
    int* __restrict__ endoff, int* __restrict__ cur,
    const int* __restrict__ bsum, int N)
{
    int i = blockIdx.x * 256 + threadIdx.x;
    if (i < N) {
        int v = endoff[i] + bsum[blockIdx.x];
        endoff[i] = v;
        cur[i] = v;
    }
}

// recs[p] = {src[e], ew[e]} sorted by dst (backward fill via atomicSub)
__global__ __launch_bounds__(256) void k_place(
    const int* __restrict__ src, const int* __restrict__ dst,
    const float* __restrict__ ew, int* __restrict__ cur,
    int2* __restrict__ recs, int E)
{
    int e = blockIdx.x * 256 + threadIdx.x;
    if (e < E) {
        int d = dst[e];
        int p = atomicSub(&cur[d], 1) - 1;
        int2 r;
        r.x = src[e];
        r.y = __float_as_int(ew[e]);
        recs[p] = r;
    }
}

// ---------------------------------------------------------------------------
// GEMM1: Y[bf16, N x 64] = X[f32, N x 128] @ W[128 x 64]
// 32 rows x 64 cols / 256-thread block; thread = 2 rows x 4 cols.
// ---------------------------------------------------------------------------
__global__ __launch_bounds__(256) void k_gemm1(
    const float* __restrict__ X, const float* __restrict__ W,
    ushort_t* __restrict__ Y)
{
    const int K = 128;
    __shared__ float sW[K * 64];
    __shared__ float sX[32 * (K + 4)];
    const int tid  = threadIdx.x;
    const int row0 = blockIdx.x * 32;

    #pragma unroll
    for (int i = tid * 4; i < K * 64; i += 256 * 4)
        *(float4*)(sW + i) = *(const float4*)(W + i);
    #pragma unroll
    for (int i = tid; i < 32 * (K / 4); i += 256) {
        int r  = i / (K / 4);
        int c4 = (i % (K / 4)) * 4;
        *(float4*)(sX + r * (K + 4) + c4) =
            *(const float4*)(X + (size_t)(row0 + r) * K + c4);
    }
    __syncthreads();

    const int c0 = (tid & 15) * 4;
    const int r0 = (tid >> 4) * 2;
    float a00 = 0.f, a01 = 0.f, a02 = 0.f, a03 = 0.f;
    float a10 = 0.f, a11 = 0.f, a12 = 0.f, a13 = 0.f;
    #pragma unroll 8
    for (int k = 0; k < K; ++k) {
        float4 wv = *(const float4*)(sW + k * 64 + c0);
        float x0 = sX[r0 * (K + 4) + k];
        float x1 = sX[(r0 + 1) * (K + 4) + k];
        a00 = fmaf(x0, wv.x, a00); a01 = fmaf(x0, wv.y, a01);
        a02 = fmaf(x0, wv.z, a02); a03 = fmaf(x0, wv.w, a03);
        a10 = fmaf(x1, wv.x, a10); a11 = fmaf(x1, wv.y, a11);
        a12 = fmaf(x1, wv.z, a12); a13 = fmaf(x1, wv.w, a13);
    }
    ushort4 p0 = make_ushort4(f2bf(a00), f2bf(a01), f2bf(a02), f2bf(a03));
    ushort4 p1 = make_ushort4(f2bf(a10), f2bf(a11), f2bf(a12), f2bf(a13));
    *(ushort4*)(Y + (size_t)(row0 + r0)     * 64 + c0) = p0;
    *(ushort4*)(Y + (size_t)(row0 + r0 + 1) * 64 + c0) = p1;
}

// ---------------------------------------------------------------------------
// GEMM2: Y[bf16, N x 64] = X[bf16, N x 64] @ W[64 x 64]
// ---------------------------------------------------------------------------
__global__ __launch_bounds__(256) void k_gemm2(
    const ushort_t* __restrict__ X, const float* __restrict__ W,
    ushort_t* __restrict__ Y)
{
    const int K = 64;
    __shared__ float sW[K * 64];
    __shared__ float sX[32 * (K + 4)];
    const int tid  = threadIdx.x;
    const int row0 = blockIdx.x * 32;

    #pragma unroll
    for (int i = tid * 4; i < K * 64; i += 256 * 4)
        *(float4*)(sW + i) = *(const float4*)(W + i);
    #pragma unroll
    for (int i = tid; i < 32 * (K / 4); i += 256) {
        int r  = i / (K / 4);
        int c4 = (i % (K / 4)) * 4;
        ushort4 v = *(const ushort4*)(X + (size_t)(row0 + r) * K + c4);
        float* o = sX + r * (K + 4) + c4;
        o[0] = bf2f(v.x); o[1] = bf2f(v.y); o[2] = bf2f(v.z); o[3] = bf2f(v.w);
    }
    __syncthreads();

    const int c0 = (tid & 15) * 4;
    const int r0 = (tid >> 4) * 2;
    float a00 = 0.f, a01 = 0.f, a02 = 0.f, a03 = 0.f;
    float a10 = 0.f, a11 = 0.f, a12 = 0.f, a13 = 0.f;
    #pragma unroll 8
    for (int k = 0; k < K; ++k) {
        float4 wv = *(const float4*)(sW + k * 64 + c0);
        float x0 = sX[r0 * (K + 4) + k];
        float x1 = sX[(r0 + 1) * (K + 4) + k];
        a00 = fmaf(x0, wv.x, a00); a01 = fmaf(x0, wv.y, a01);
        a02 = fmaf(x0, wv.z, a02); a03 = fmaf(x0, wv.w, a03);
        a10 = fmaf(x1, wv.x, a10); a11 = fmaf(x1, wv.y, a11);
        a12 = fmaf(x1, wv.z, a12); a13 = fmaf(x1, wv.w, a13);
    }
    ushort4 p0 = make_ushort4(f2bf(a00), f2bf(a01), f2bf(a02), f2bf(a03));
    ushort4 p1 = make_ushort4(f2bf(a10), f2bf(a11), f2bf(a12), f2bf(a13));
    *(ushort4*)(Y + (size_t)(row0 + r0)     * 64 + c0) = p0;
    *(ushort4*)(Y + (size_t)(row0 + r0 + 1) * 64 + c0) = p1;
}

// ---------------------------------------------------------------------------
// Gather-reduce: one wave per node, lane = channel.
// acc[c] = sum_{j in [end-deg, end)} w_j * H[src_j][c];  v = acc + bias[c]
// RELU: v = max(v,0).  OUT_BF16: store bf16, else fp32.
// ---------------------------------------------------------------------------
template<bool RELU, bool OUT_BF16>
__global__ __launch_bounds__(256) void k_gather(
    const ushort_t* __restrict__ H, const int2* __restrict__ recs,
    const int* __restrict__ endoff, const int* __restrict__ hist,
    const float* __restrict__ bias, void* __restrict__ out)
{
    const int wid  = threadIdx.x >> 6;
    const int lane = threadIdx.x & 63;
    const int n    = blockIdx.x * 4 + wid;   // grid = N/4 exactly

    const int end   = endoff[n];
    const int start = end - hist[n];

    float acc = 0.f;
    for (int j = start; j < end; ++j) {
        int2 r = recs[j];                      // wave-uniform -> scalar load
        float w = __int_as_float(r.y);
        acc = fmaf(w, bf2f(H[(size_t)r.x * 64 + lane]), acc);
    }
    float v = acc + bias[lane];
    if (RELU) v = fmaxf(v, 0.f);
    if (OUT_BF16)
        ((ushort_t*)out)[(size_t)n * 64 + lane] = f2bf(v);
    else
        ((float*)out)[(size_t)n * 64 + lane] = v;
}

// ---------------------------------------------------------------------------
extern "C" void kernel_launch(void* const* d_in, const int* in_sizes, int n_in,
                              void* d_out, int out_size, void* d_ws, size_t ws_size,
                              hipStream_t stream) {
    const float* x   = (const float*)d_in[0];
    const int*   ei  = (const int*)  d_in[1];
    const float* ew  = (const float*)d_in[2];
    const float* w1  = (const float*)d_in[3];
    const float* b1  = (const float*)d_in[4];
    const float* w2  = (const float*)d_in[5];
    const float* b2  = (const float*)d_in[6];
    float* out = (float*)d_out;

    const int N = N_NODES, E = N_EDGES;
    const int* src = ei;
    const int* dst = ei + E;

    // workspace layout (39.6 MB total)
    char* p = (char*)d_ws;
    ushort_t* bufA  = (ushort_t*)p;                 p += (size_t)N * 64 * 2;  // 12.8MB: h1, then h2
    ushort_t* bufB  = (ushort_t*)p;                 p += (size_t)N * 64 * 2;  // 12.8MB: h1'
    int*      hist  = (int*)p;                      p += (size_t)N * 4;
    int*      endo  = (int*)p;                      p += (size_t)N * 4;
    int*      cur   = (int*)p;                      p += (size_t)N * 4;
    int*      bsum  = (int*)p;                      p += 16 * ((SCAN_BLOCKS * 4 + 15) / 16);
    int2*     recs  = (int2*)p;                     p += (size_t)E * 8;       // 12.8MB

    // ---- CSR build (independent of GEMM1; runs once, used by both layers)
    hipMemsetAsync(hist, 0, (size_t)N * 4, stream);
    k_hist <<<E / 256, 256, 0, stream>>>(dst, hist, E);
    k_scan1<<<SCAN_BLOCKS, 256, 0, stream>>>(hist, endo, bsum, N);
    k_scan2<<<1, 512, 0, stream>>>(bsum, SCAN_BLOCKS);
    k_scan3<<<SCAN_BLOCKS, 256, 0, stream>>>(endo, cur, bsum, N);
    k_place<<<E / 256, 256, 0, stream>>>(src, dst, ew, cur, recs, E);

    // ---- layer 1: h1 = x@w1 ; h1' = relu(gather(h1) + b1)
    k_gemm1<<<N / 32, 256, 0, stream>>>(x, w1, bufA);
    k_gather<true, true><<<N / 4, 256, 0, stream>>>(bufA, recs, endo, hist, b1, bufB);

    // ---- layer 2: h2 = h1'@w2 ; out = gather(h2) + b2
    k_gemm2<<<N / 32, 256, 0, stream>>>(bufB, w2, bufA);
    k_gather<false, false><<<N / 4, 256, 0, stream>>>(bufA, recs, endo, hist, b2, out);
}

// Round 3
// 465.859 us; speedup vs baseline: 6.1453x; 1.3595x over previous
//
#include <hip/hip_runtime.h>
#include <hip/hip_bf16.h>

// GCN 2-layer: h1' = relu(S·(x@w1) + b1); out = S·(h1'@w2) + b2
// CSR-by-dst counting sort, then gather-reduce (no atomics in hot loops).
// Gather: wave per node, 4-way split (16 lanes x ushort4 per edge) -> 4 edges
// per load instruction, recs preloaded per-wave and shfl-broadcast.
// Intermediates bf16. N=100000, E=1600000, IN=128, HID=64, OUT=64.

#define N_NODES 100000
#define N_EDGES 1600000
#define SCAN_BLOCKS 391   // ceil(100000/256)

typedef unsigned short ushort_t;
typedef unsigned int uint_t;

static __device__ __forceinline__ float bf2f(ushort_t h) {
    return __uint_as_float(((uint_t)h) << 16);
}
static __device__ __forceinline__ ushort_t f2bf(float f) {
    uint_t u = __float_as_uint(f);
    u = (u + 0x7FFF + ((u >> 16) & 1)) >> 16;   // RNE
    return (ushort_t)u;
}

// ---------------------------------------------------------------------------
// CSR build: histogram -> scan -> placement
// ---------------------------------------------------------------------------
__global__ __launch_bounds__(256) void k_hist(
    const int* __restrict__ dst, int* __restrict__ hist, int E)
{
    int e = blockIdx.x * 256 + threadIdx.x;
    if (e < E) atomicAdd(&hist[dst[e]], 1);
}

__global__ __launch_bounds__(256) void k_scan1(
    const int* __restrict__ hist, int* __restrict__ endoff,
    int* __restrict__ bsum, int N)
{
    __shared__ int s[256];
    int t = threadIdx.x;
    int i = blockIdx.x * 256 + t;
    int v = (i < N) ? hist[i] : 0;
    s[t] = v;
    #pragma unroll
    for (int off = 1; off < 256; off <<= 1) {
        __syncthreads();
        int add = (t >= off) ? s[t - off] : 0;
        __syncthreads();
        s[t] += add;
    }
    __syncthreads();
    if (i < N) endoff[i] = s[t];
    if (t == 255) bsum[blockIdx.x] = s[255];
}

__global__ __launch_bounds__(512) void k_scan2(int* __restrict__ bsum, int nb)
{
    __shared__ int s[512];
    int t = threadIdx.x;
    s[t] = (t < nb) ? bsum[t] : 0;
    #pragma unroll
    for (int off = 1; off < 512; off <<= 1) {
        __syncthreads();
        int add = (t >= off) ? s[t - off] : 0;
        __syncthreads();
        s[t] += add;
    }
    __syncthreads();
    if (t < nb) bsum[t] = (t == 0) ? 0 : s[t - 1];
}

__global__ __launch_bounds__(256) void k_scan3(
    int* __restrict__ endoff, int* __restrict__ cur,
    const int* __restrict__ bsum, int N)
{
    int i = blockIdx.x * 256 + threadIdx.x;
    if (i < N) {
        int v = endoff[i] + bsum[blockIdx.x];
        endoff[i] = v;
        cur[i] = v;
    }
}

__global__ __launch_bounds__(256) void k_place(
    const int* __restrict__ src, const int* __restrict__ dst,
    const float* __restrict__ ew, int* __restrict__ cur,
    int2* __restrict__ recs, int E)
{
    int e = blockIdx.x * 256 + threadIdx.x;
    if (e < E) {
        int d = dst[e];
        int p = atomicSub(&cur[d], 1) - 1;
        int2 r;
        r.x = src[e];
        r.y = __float_as_int(ew[e]);
        recs[p] = r;
    }
}

// ---------------------------------------------------------------------------
// GEMM1: Y[bf16, N x 64] = X[f32, N x 128] @ W[128 x 64]
// 64 rows x 64 cols / 256-thread block; thread = 4 rows x 4 cols.
// ---------------------------------------------------------------------------
__global__ __launch_bounds__(256) void k_gemm1(
    const float* __restrict__ X, const float* __restrict__ W,
    ushort_t* __restrict__ Y, int N)
{
    const int K = 128;
    __shared__ float sW[K * 64];          // 32 KB
    __shared__ float sX[64 * (K + 4)];    // 33.8 KB
    const int tid  = threadIdx.x;
    const int row0 = blockIdx.x * 64;

    #pragma unroll
    for (int i = tid * 4; i < K * 64; i += 256 * 4)
        *(float4*)(sW + i) = *(const float4*)(W + i);
    #pragma unroll
    for (int i = tid; i < 64 * (K / 4); i += 256) {
        int r  = i >> 5;             // K/4 = 32 float4 per row
        int c4 = (i & 31) * 4;
        int rg = row0 + r; if (rg > N - 1) rg = N - 1;   // clamp (dup read)
        *(float4*)(sX + r * (K + 4) + c4) =
            *(const float4*)(X + (size_t)rg * K + c4);
    }
    __syncthreads();

    const int c0 = (tid & 15) * 4;
    const int r0 = (tid >> 4) * 4;
    float acc[4][4];
    #pragma unroll
    for (int i = 0; i < 4; ++i)
        #pragma unroll
        for (int j = 0; j < 4; ++j) acc[i][j] = 0.f;

    for (int k4 = 0; k4 < K; k4 += 4) {
        float4 xv[4];
        #pragma unroll
        for (int i = 0; i < 4; ++i)
            xv[i] = *(const float4*)(sX + (r0 + i) * (K + 4) + k4);
        #pragma unroll
        for (int kk = 0; kk < 4; ++kk) {
            float4 wv = *(const float4*)(sW + (k4 + kk) * 64 + c0);
            #pragma unroll
            for (int i = 0; i < 4; ++i) {
                float xs = (kk == 0) ? xv[i].x : (kk == 1) ? xv[i].y
                         : (kk == 2) ? xv[i].z : xv[i].w;
                acc[i][0] = fmaf(xs, wv.x, acc[i][0]);
                acc[i][1] = fmaf(xs, wv.y, acc[i][1]);
                acc[i][2] = fmaf(xs, wv.z, acc[i][2]);
                acc[i][3] = fmaf(xs, wv.w, acc[i][3]);
            }
        }
    }
    #pragma unroll
    for (int i = 0; i < 4; ++i) {
        int rg = row0 + r0 + i;
        if (rg < N) {
            ushort4 pk = make_ushort4(f2bf(acc[i][0]), f2bf(acc[i][1]),
                                      f2bf(acc[i][2]), f2bf(acc[i][3]));
            *(ushort4*)(Y + (size_t)rg * 64 + c0) = pk;
        }
    }
}

// ---------------------------------------------------------------------------
// GEMM2: Y[bf16, N x 64] = X[bf16, N x 64] @ W[64 x 64]
// ---------------------------------------------------------------------------
__global__ __launch_bounds__(256) void k_gemm2(
    const ushort_t* __restrict__ X, const float* __restrict__ W,
    ushort_t* __restrict__ Y, int N)
{
    const int K = 64;
    __shared__ float sW[K * 64];          // 16 KB
    __shared__ float sX[64 * (K + 4)];    // 17.4 KB
    const int tid  = threadIdx.x;
    const int row0 = blockIdx.x * 64;

    #pragma unroll
    for (int i = tid * 4; i < K * 64; i += 256 * 4)
        *(float4*)(sW + i) = *(const float4*)(W + i);
    #pragma unroll
    for (int i = tid; i < 64 * (K / 4); i += 256) {
        int r  = i >> 4;             // K/4 = 16 ushort4 per row
        int c4 = (i & 15) * 4;
        int rg = row0 + r; if (rg > N - 1) rg = N - 1;
        ushort4 v = *(const ushort4*)(X + (size_t)rg * K + c4);
        float* o = sX + r * (K + 4) + c4;
        o[0] = bf2f(v.x); o[1] = bf2f(v.y); o[2] = bf2f(v.z); o[3] = bf2f(v.w);
    }
    __syncthreads();

    const int c0 = (tid & 15) * 4;
    const int r0 = (tid >> 4) * 4;
    float acc[4][4];
    #pragma unroll
    for (int i = 0; i < 4; ++i)
        #pragma unroll
        for (int j = 0; j < 4; ++j) acc[i][j] = 0.f;

    for (int k4 = 0; k4 < K; k4 += 4) {
        float4 xv[4];
        #pragma unroll
        for (int i = 0; i < 4; ++i)
            xv[i] = *(const float4*)(sX + (r0 + i) * (K + 4) + k4);
        #pragma unroll
        for (int kk = 0; kk < 4; ++kk) {
            float4 wv = *(const float4*)(sW + (k4 + kk) * 64 + c0);
            #pragma unroll
            for (int i = 0; i < 4; ++i) {
                float xs = (kk == 0) ? xv[i].x : (kk == 1) ? xv[i].y
                         : (kk == 2) ? xv[i].z : xv[i].w;
                acc[i][0] = fmaf(xs, wv.x, acc[i][0]);
                acc[i][1] = fmaf(xs, wv.y, acc[i][1]);
                acc[i][2] = fmaf(xs, wv.z, acc[i][2]);
                acc[i][3] = fmaf(xs, wv.w, acc[i][3]);
            }
        }
    }
    #pragma unroll
    for (int i = 0; i < 4; ++i) {
        int rg = row0 + r0 + i;
        if (rg < N) {
            ushort4 pk = make_ushort4(f2bf(acc[i][0]), f2bf(acc[i][1]),
                                      f2bf(acc[i][2]), f2bf(acc[i][3]));
            *(ushort4*)(Y + (size_t)rg * 64 + c0) = pk;
        }
    }
}

// ---------------------------------------------------------------------------
// Gather-reduce: one wave per node. 4-way split: quad q = lane>>4 handles
// edge jj+q; 16 lanes per edge, each loading ushort4 (4 channels, 8 B).
// recs preloaded 64-wide per wave, broadcast via shfl. Zero atomics.
// ---------------------------------------------------------------------------
template<bool RELU, bool OUT_BF16>
__global__ __launch_bounds__(256) void k_gather(
    const ushort_t* __restrict__ H, const int2* __restrict__ recs,
    const int* __restrict__ endoff, const int* __restrict__ hist,
    const float* __restrict__ bias, void* __restrict__ out)
{
    const int wid  = threadIdx.x >> 6;
    const int lane = threadIdx.x & 63;
    const int n    = blockIdx.x * 4 + wid;   // grid = N/4 exactly

    const int end   = endoff[n];
    const int start = end - hist[n];
    const int q     = lane >> 4;          // which edge in the quad
    const int c4    = (lane & 15) * 4;    // channel base

    float a0 = 0.f, a1 = 0.f, a2 = 0.f, a3 = 0.f;

    for (int base = start; base < end; base += 64) {
        const int m = (end - base < 64) ? (end - base) : 64;
        int2 r = recs[base + (lane < m ? lane : 0)];
        float rw = __int_as_float(r.y);
        #pragma unroll 4
        for (int jj = 0; jj < m; jj += 4) {
            int idx = jj + q;
            int s   = __shfl(r.x, idx);
            float w = __shfl(rw, idx);
            if (idx >= m) w = 0.f;
            ushort4 hv = *(const ushort4*)(H + (size_t)s * 64 + c4);
            a0 = fmaf(w, bf2f(hv.x), a0);
            a1 = fmaf(w, bf2f(hv.y), a1);
            a2 = fmaf(w, bf2f(hv.z), a2);
            a3 = fmaf(w, bf2f(hv.w), a3);
        }
    }
    // reduce across the 4 quads (lanes i, i+16, i+32, i+48)
    a0 += __shfl_down(a0, 32); a1 += __shfl_down(a1, 32);
    a2 += __shfl_down(a2, 32); a3 += __shfl_down(a3, 32);
    a0 += __shfl_down(a0, 16); a1 += __shfl_down(a1, 16);
    a2 += __shfl_down(a2, 16); a3 += __shfl_down(a3, 16);

    if (lane < 16) {
        float4 bv = *(const float4*)(bias + c4);
        float v0 = a0 + bv.x, v1 = a1 + bv.y, v2 = a2 + bv.z, v3 = a3 + bv.w;
        if (RELU) {
            v0 = fmaxf(v0, 0.f); v1 = fmaxf(v1, 0.f);
            v2 = fmaxf(v2, 0.f); v3 = fmaxf(v3, 0.f);
        }
        if (OUT_BF16) {
            ushort4 pk = make_ushort4(f2bf(v0), f2bf(v1), f2bf(v2), f2bf(v3));
            *(ushort4*)((ushort_t*)out + (size_t)n * 64 + c4) = pk;
        } else {
            *(float4*)((float*)out + (size_t)n * 64 + c4) =
                make_float4(v0, v1, v2, v3);
        }
    }
}

// ---------------------------------------------------------------------------
extern "C" void kernel_launch(void* const* d_in, const int* in_sizes, int n_in,
                              void* d_out, int out_size, void* d_ws, size_t ws_size,
                              hipStream_t stream) {
    const float* x   = (const float*)d_in[0];
    const int*   ei  = (const int*)  d_in[1];
    const float* ew  = (const float*)d_in[2];
    const float* w1  = (const float*)d_in[3];
    const float* b1  = (const float*)d_in[4];
    const float* w2  = (const float*)d_in[5];
    const float* b2  = (const float*)d_in[6];
    float* out = (float*)d_out;

    const int N = N_NODES, E = N_EDGES;
    const int* src = ei;
    const int* dst = ei + E;

    char* p = (char*)d_ws;
    ushort_t* bufA  = (ushort_t*)p;                 p += (size_t)N * 64 * 2;  // h1, then h2
    ushort_t* bufB  = (ushort_t*)p;                 p += (size_t)N * 64 * 2;  // h1'
    int*      hist  = (int*)p;                      p += (size_t)N * 4;
    int*      endo  = (int*)p;                      p += (size_t)N * 4;
    int*      cur   = (int*)p;                      p += (size_t)N * 4;
    int*      bsum  = (int*)p;                      p += 16 * ((SCAN_BLOCKS * 4 + 15) / 16);
    int2*     recs  = (int2*)p;                     p += (size_t)E * 8;

    // ---- CSR build
    hipMemsetAsync(hist, 0, (size_t)N * 4, stream);
    k_hist <<<E / 256, 256, 0, stream>>>(dst, hist, E);
    k_scan1<<<SCAN_BLOCKS, 256, 0, stream>>>(hist, endo, bsum, N);
    k_scan2<<<1, 512, 0, stream>>>(bsum, SCAN_BLOCKS);
    k_scan3<<<SCAN_BLOCKS, 256, 0, stream>>>(endo, cur, bsum, N);
    k_place<<<E / 256, 256, 0, stream>>>(src, dst, ew, cur, recs, E);

    // ---- layer 1
    k_gemm1<<<(N + 63) / 64, 256, 0, stream>>>(x, w1, bufA, N);
    k_gather<true, true><<<N / 4, 256, 0, stream>>>(bufA, recs, endo, hist, b1, bufB);

    // ---- layer 2
    k_gemm2<<<(N + 63) / 64, 256, 0, stream>>>(bufB, w2, bufA, N);
    k_gather<false, false><<<N / 4, 256, 0, stream>>>(bufA, recs, endo, hist, b2, out);
}